// Round 1
// baseline (267.857 us; speedup 1.0000x reference)
//
#include <hip/hip_runtime.h>
#include <cmath>

#define BN 32
#define AN 32768
#define GN 64

// Workspace layout (bytes):
// [0,128):    int   num_pos[32]
// [128,256):  float loc_sum[32]
// [256,384):  float posconf[32]
// [384,512):  float negconf[32]
// [512, 512+BN*AN): u8 posflag[B*A]
#define WS_NUMPOS(ws)  ((int*)(ws))
#define WS_LOC(ws)     ((float*)((char*)(ws) + 128))
#define WS_PCONF(ws)   ((float*)((char*)(ws) + 256))
#define WS_NCONF(ws)   ((float*)((char*)(ws) + 384))
#define WS_POS(ws)     ((unsigned char*)((char*)(ws) + 512))

__device__ __forceinline__ float iou_val(float ax0, float ay0, float ax1, float ay1, float aarea,
                                         float gx0, float gy0, float gx1, float gy1, float garea) {
    float ix0 = fmaxf(ax0, gx0), iy0 = fmaxf(ay0, gy0);
    float ix1 = fminf(ax1, gx1), iy1 = fminf(ay1, gy1);
    float iw = fmaxf(ix1 - ix0, 0.0f), ih = fmaxf(iy1 - iy0, 0.0f);
    float inter = iw * ih;
    return inter / (aarea + garea - inter + 1e-6f);
}

// Kernel 1: per (image, gt) argmax over anchors of IoU -> force that anchor positive.
// One wave per gt. grid = (GN/4, BN), block = 256 (4 waves).
__global__ void k_best_anchor(const float* __restrict__ anchors,
                              const float* __restrict__ gt,
                              unsigned char* __restrict__ posflag) {
    int wave = threadIdx.x >> 6;
    int lane = threadIdx.x & 63;
    int g = blockIdx.x * 4 + wave;
    int b = blockIdx.y;

    float4 gb = ((const float4*)gt)[b * GN + g];
    float garea = (gb.z - gb.x) * (gb.w - gb.y);

    float best = -1.0f;
    int bidx = 0;
    for (int a = lane; a < AN; a += 64) {
        float4 ab = ((const float4*)anchors)[a];
        float aarea = (ab.z - ab.x) * (ab.w - ab.y);
        float iou = iou_val(ab.x, ab.y, ab.z, ab.w, aarea, gb.x, gb.y, gb.z, gb.w, garea);
        if (iou > best) { best = iou; bidx = a; }  // strict > keeps smallest index (first occurrence)
    }
    // wave reduce: max iou, tie -> min index (matches jnp.argmax first-occurrence)
    for (int off = 32; off; off >>= 1) {
        float ob = __shfl_xor(best, off);
        int   oi = __shfl_xor(bidx, off);
        if (ob > best || (ob == best && oi < bidx)) { best = ob; bidx = oi; }
    }
    if (lane == 0) posflag[(size_t)b * AN + bidx] = 1;
}

// Kernel 2: per-anchor pass. best gt (max/argmax over G), pos mask, smooth-L1 loc, pos-BCE.
// grid = (AN/256, BN), block = 256.
__global__ void k_anchor_pass(const float* __restrict__ bbox,
                              const float* __restrict__ conf,
                              const float* __restrict__ anchors,
                              const float* __restrict__ gt,
                              unsigned char* __restrict__ posflag,
                              int* __restrict__ num_pos,
                              float* __restrict__ loc_sum,
                              float* __restrict__ posconf) {
    __shared__ float4 sg[GN];     // gt corners
    __shared__ float  sga[GN];    // gt area
    __shared__ float4 sgcs[GN];   // gt center-size
    __shared__ float  s_loc[4], s_pc[4];
    __shared__ int    s_np[4];

    int b = blockIdx.y;
    int tid = threadIdx.x;
    if (tid < GN) {
        float4 g = ((const float4*)gt)[b * GN + tid];
        sg[tid] = g;
        sga[tid] = (g.z - g.x) * (g.w - g.y);
        sgcs[tid] = make_float4((g.x + g.z) * 0.5f, (g.y + g.w) * 0.5f, g.z - g.x, g.w - g.y);
    }
    __syncthreads();

    int a = blockIdx.x * 256 + tid;
    size_t ia = (size_t)b * AN + a;

    float4 ab = ((const float4*)anchors)[a];
    float aarea = (ab.z - ab.x) * (ab.w - ab.y);

    float best = -1.0f;
    int bidx = 0;
#pragma unroll 8
    for (int g = 0; g < GN; ++g) {
        float4 gb = sg[g];
        float iou = iou_val(ab.x, ab.y, ab.z, ab.w, aarea, gb.x, gb.y, gb.z, gb.w, sga[g]);
        if (iou > best) { best = iou; bidx = g; }  // first occurrence
    }

    bool p = (best > 0.5f) || (posflag[ia] != 0);
    posflag[ia] = p ? (unsigned char)1 : (unsigned char)0;

    float locv = 0.0f, pcv = 0.0f;
    if (p) {
        float4 bb = ((const float4*)bbox)[ia];
        float4 m = sgcs[bidx];
        float d0 = (bb.x + bb.z) * 0.5f - m.x;
        float d1 = (bb.y + bb.w) * 0.5f - m.y;
        float d2 = (bb.z - bb.x) - m.z;
        float d3 = (bb.w - bb.y) - m.w;
        float s = 0.0f;
        {
            float ad = fabsf(d0); s += (ad < 1.0f) ? 0.5f * d0 * d0 : ad - 0.5f;
            ad = fabsf(d1); s += (ad < 1.0f) ? 0.5f * d1 * d1 : ad - 0.5f;
            ad = fabsf(d2); s += (ad < 1.0f) ? 0.5f * d2 * d2 : ad - 0.5f;
            ad = fabsf(d3); s += (ad < 1.0f) ? 0.5f * d3 * d3 : ad - 0.5f;
        }
        locv = s;
        float pc = conf[ia];
        float lp = fmaxf(logf(pc), -100.0f);
        pcv = -lp;
    }
    int npv = p ? 1 : 0;

    // wave reduce
    for (int off = 32; off; off >>= 1) {
        locv += __shfl_xor(locv, off);
        pcv  += __shfl_xor(pcv, off);
        npv  += __shfl_xor(npv, off);
    }
    int wave = tid >> 6, lane = tid & 63;
    if (lane == 0) { s_loc[wave] = locv; s_pc[wave] = pcv; s_np[wave] = npv; }
    __syncthreads();
    if (tid == 0) {
        float L = 0.0f, P = 0.0f; int N = 0;
        for (int w = 0; w < 4; ++w) { L += s_loc[w]; P += s_pc[w]; N += s_np[w]; }
        if (N) atomicAdd(&num_pos[b], N);
        atomicAdd(&loc_sum[b], L);
        atomicAdd(&posconf[b], P);
    }
}

// Kernel 3: per-image hard-negative mining: sum of top-k of neg_loss.
// Exact radix-select (4 x 8-bit rounds) on float bit patterns (all values >= +0).
// grid = BN, block = 1024. 128KB LDS for the per-image value array.
__global__ __launch_bounds__(1024) void k_topk(const float* __restrict__ conf,
                                               const unsigned char* __restrict__ posflag,
                                               const int* __restrict__ num_pos,
                                               float* __restrict__ negconf) {
    __shared__ float vals[AN];            // 128 KiB
    __shared__ unsigned int hist[256];
    __shared__ float red[16];
    __shared__ unsigned int s_sel, s_krem;

    int b = blockIdx.x;
    int tid = threadIdx.x;

    for (int i = tid; i < AN; i += 1024) {
        size_t idx = (size_t)b * AN + i;
        float p = conf[idx];
        float l = fmaxf(log1pf(-p), -100.0f);   // log(1-p), clamped like torch BCELoss
        float v = posflag[idx] ? 0.0f : -l;     // neg_loss (>= 0; exactly +0 for positives)
        vals[i] = v;
    }
    __syncthreads();

    int np = num_pos[b];
    int k = min(3 * np, AN - np);

    float result = 0.0f;
    if (k > 0) {
        unsigned int prefix = 0;
        unsigned int krem = (unsigned int)k;
        for (int shift = 24; shift >= 0; shift -= 8) {
            if (tid < 256) hist[tid] = 0;
            __syncthreads();
            unsigned int hm = (shift == 24) ? 0u : (0xFFFFFFFFu << (shift + 8));
            for (int i = tid; i < AN; i += 1024) {
                unsigned int key = __float_as_uint(vals[i]);
                if ((key & hm) == prefix) atomicAdd(&hist[(key >> shift) & 0xFFu], 1u);
            }
            __syncthreads();
            if (tid == 0) {
                unsigned int cum = 0; int sel = 0; unsigned int nk = 1;
                for (int bb = 255; bb >= 0; --bb) {
                    unsigned int c = hist[bb];
                    if (cum + c >= krem) { sel = bb; nk = krem - cum; break; }
                    cum += c;
                }
                s_sel = (unsigned int)sel;
                s_krem = nk;
            }
            __syncthreads();
            prefix |= (s_sel << shift);
            krem = s_krem;
            __syncthreads();
        }
        float T = __uint_as_float(prefix);   // exact value of the k-th largest element
        float part = 0.0f;
        for (int i = tid; i < AN; i += 1024) {
            float v = vals[i];
            if (v > T) part += v;
        }
        for (int off = 32; off; off >>= 1) part += __shfl_xor(part, off);
        int wave = tid >> 6, lane = tid & 63;
        if (lane == 0) red[wave] = part;
        __syncthreads();
        if (tid == 0) {
            float t = 0.0f;
            for (int w = 0; w < 16; ++w) t += red[w];
            result = t + (float)krem * T;    // krem copies of the boundary value
            negconf[b] = result;
        }
    } else {
        if (tid == 0) negconf[b] = 0.0f;
    }
}

// Kernel 4: final reduction over images. 1 block, 64 threads.
__global__ void k_final(const int* __restrict__ num_pos,
                        const float* __restrict__ loc_sum,
                        const float* __restrict__ posconf,
                        const float* __restrict__ negconf,
                        float* __restrict__ out) {
    int tid = threadIdx.x;
    int np = 0; float lc = 0.0f, pc = 0.0f, nc = 0.0f;
    if (tid < BN) {
        np = num_pos[tid];
        lc = loc_sum[tid];
        pc = posconf[tid];
        nc = negconf[tid];
    }
    for (int off = 32; off; off >>= 1) {
        np += __shfl_xor(np, off);
        lc += __shfl_xor(lc, off);
        pc += __shfl_xor(pc, off);
        nc += __shfl_xor(nc, off);
    }
    if (tid == 0) {
        float tp = (float)max(1, np);
        float loc_loss = lc / tp;
        float conf_loss = (pc + nc) / tp;
        out[0] = loc_loss + conf_loss;
        out[1] = conf_loss;
        out[2] = loc_loss;
    }
}

extern "C" void kernel_launch(void* const* d_in, const int* in_sizes, int n_in,
                              void* d_out, int out_size, void* d_ws, size_t ws_size,
                              hipStream_t stream) {
    const float* bbox    = (const float*)d_in[0];   // [B,A,4]
    const float* conf    = (const float*)d_in[1];   // [B,A]
    const float* anchors = (const float*)d_in[2];   // [A,4]
    const float* gt      = (const float*)d_in[3];   // [B,G,4]
    float* out = (float*)d_out;

    // Zero flags + accumulators (deterministic per launch; graph-capture safe).
    hipMemsetAsync(d_ws, 0, 512 + (size_t)BN * AN, stream);

    dim3 g1(GN / 4, BN);
    k_best_anchor<<<g1, 256, 0, stream>>>(anchors, gt, WS_POS(d_ws));

    dim3 g2(AN / 256, BN);
    k_anchor_pass<<<g2, 256, 0, stream>>>(bbox, conf, anchors, gt, WS_POS(d_ws),
                                          WS_NUMPOS(d_ws), WS_LOC(d_ws), WS_PCONF(d_ws));

    k_topk<<<BN, 1024, 0, stream>>>(conf, WS_POS(d_ws), WS_NUMPOS(d_ws), WS_NCONF(d_ws));

    k_final<<<1, 64, 0, stream>>>(WS_NUMPOS(d_ws), WS_LOC(d_ws), WS_PCONF(d_ws),
                                  WS_NCONF(d_ws), out);
}

// Round 2
// 215.181 us; speedup vs baseline: 1.2448x; 1.2448x over previous
//
#include <hip/hip_runtime.h>
#include <cmath>

#define BN 32
#define AN 32768
#define GN 64

// Workspace layout (bytes):
// [0,128):    int   num_pos[32]
// [128,256):  float loc_sum[32]
// [256,384):  float posconf[32]
// [384,512):  float negconf[32]
// [512, 512+BN*AN): u8 posflag[B*A]
#define WS_NUMPOS(ws)  ((int*)(ws))
#define WS_LOC(ws)     ((float*)((char*)(ws) + 128))
#define WS_PCONF(ws)   ((float*)((char*)(ws) + 256))
#define WS_NCONF(ws)   ((float*)((char*)(ws) + 384))
#define WS_POS(ws)     ((unsigned char*)((char*)(ws) + 512))

__device__ __forceinline__ float iou_val(float ax0, float ay0, float ax1, float ay1, float aarea,
                                         float gx0, float gy0, float gx1, float gy1, float garea) {
    float ix0 = fmaxf(ax0, gx0), iy0 = fmaxf(ay0, gy0);
    float ix1 = fminf(ax1, gx1), iy1 = fminf(ay1, gy1);
    float iw = fmaxf(ix1 - ix0, 0.0f), ih = fmaxf(iy1 - iy0, 0.0f);
    float inter = iw * ih;
    return inter / (aarea + garea - inter + 1e-6f);
}

// Kernel 1: per (image, gt) argmax over anchors of IoU -> force that anchor positive.
// One 512-thread block per (g, b). Each thread scans 64 anchors; reduction via
// packed u64 key = (iou_bits << 32) | ~anchor_idx  (max key == max iou, ties -> min idx,
// matching jnp.argmax first-occurrence). IoU >= 0 so float bits are monotonic.
__global__ __launch_bounds__(512) void k_best_anchor(const float* __restrict__ anchors,
                                                     const float* __restrict__ gt,
                                                     unsigned char* __restrict__ posflag) {
    __shared__ unsigned long long sred[8];
    int g = blockIdx.x;
    int b = blockIdx.y;
    int tid = threadIdx.x;

    float4 gb = ((const float4*)gt)[b * GN + g];   // uniform across block -> scalar loads
    float garea = (gb.z - gb.x) * (gb.w - gb.y);

    float best = -1.0f;
    int bidx = 0;
    for (int a = tid; a < AN; a += 512) {
        float4 ab = ((const float4*)anchors)[a];
        float aarea = (ab.z - ab.x) * (ab.w - ab.y);
        float iou = iou_val(ab.x, ab.y, ab.z, ab.w, aarea, gb.x, gb.y, gb.z, gb.w, garea);
        if (iou > best) { best = iou; bidx = a; }  // strict > keeps smallest index in stride class
    }
    unsigned long long key = ((unsigned long long)__float_as_uint(best) << 32)
                           | (unsigned int)(~bidx);
    for (int off = 32; off; off >>= 1) {
        unsigned long long ok = __shfl_xor(key, off);
        key = (ok > key) ? ok : key;
    }
    int wave = tid >> 6, lane = tid & 63;
    if (lane == 0) sred[wave] = key;
    __syncthreads();
    if (tid == 0) {
        unsigned long long k = sred[0];
        for (int w = 1; w < 8; ++w) if (sred[w] > k) k = sred[w];
        int a = (int)(unsigned int)(~(unsigned int)k);
        posflag[(size_t)b * AN + a] = 1;
    }
}

// Kernel 2: per-anchor pass. best gt (max/argmax over G), pos mask, smooth-L1 loc, pos-BCE.
// grid = (AN/256, BN), block = 256.
__global__ void k_anchor_pass(const float* __restrict__ bbox,
                              const float* __restrict__ conf,
                              const float* __restrict__ anchors,
                              const float* __restrict__ gt,
                              unsigned char* __restrict__ posflag,
                              int* __restrict__ num_pos,
                              float* __restrict__ loc_sum,
                              float* __restrict__ posconf) {
    __shared__ float4 sg[GN];     // gt corners
    __shared__ float  sga[GN];    // gt area
    __shared__ float4 sgcs[GN];   // gt center-size
    __shared__ float  s_loc[4], s_pc[4];
    __shared__ int    s_np[4];

    int b = blockIdx.y;
    int tid = threadIdx.x;
    if (tid < GN) {
        float4 g = ((const float4*)gt)[b * GN + tid];
        sg[tid] = g;
        sga[tid] = (g.z - g.x) * (g.w - g.y);
        sgcs[tid] = make_float4((g.x + g.z) * 0.5f, (g.y + g.w) * 0.5f, g.z - g.x, g.w - g.y);
    }
    __syncthreads();

    int a = blockIdx.x * 256 + tid;
    size_t ia = (size_t)b * AN + a;

    float4 ab = ((const float4*)anchors)[a];
    float aarea = (ab.z - ab.x) * (ab.w - ab.y);

    float best = -1.0f;
    int bidx = 0;
#pragma unroll 8
    for (int g = 0; g < GN; ++g) {
        float4 gb = sg[g];
        float iou = iou_val(ab.x, ab.y, ab.z, ab.w, aarea, gb.x, gb.y, gb.z, gb.w, sga[g]);
        if (iou > best) { best = iou; bidx = g; }  // first occurrence
    }

    bool p = (best > 0.5f) || (posflag[ia] != 0);
    posflag[ia] = p ? (unsigned char)1 : (unsigned char)0;

    float locv = 0.0f, pcv = 0.0f;
    if (p) {
        float4 bb = ((const float4*)bbox)[ia];
        float4 m = sgcs[bidx];
        float d0 = (bb.x + bb.z) * 0.5f - m.x;
        float d1 = (bb.y + bb.w) * 0.5f - m.y;
        float d2 = (bb.z - bb.x) - m.z;
        float d3 = (bb.w - bb.y) - m.w;
        float s = 0.0f;
        {
            float ad = fabsf(d0); s += (ad < 1.0f) ? 0.5f * d0 * d0 : ad - 0.5f;
            ad = fabsf(d1); s += (ad < 1.0f) ? 0.5f * d1 * d1 : ad - 0.5f;
            ad = fabsf(d2); s += (ad < 1.0f) ? 0.5f * d2 * d2 : ad - 0.5f;
            ad = fabsf(d3); s += (ad < 1.0f) ? 0.5f * d3 * d3 : ad - 0.5f;
        }
        locv = s;
        float pc = conf[ia];
        float lp = fmaxf(logf(pc), -100.0f);
        pcv = -lp;
    }
    int npv = p ? 1 : 0;

    // wave reduce
    for (int off = 32; off; off >>= 1) {
        locv += __shfl_xor(locv, off);
        pcv  += __shfl_xor(pcv, off);
        npv  += __shfl_xor(npv, off);
    }
    int wave = tid >> 6, lane = tid & 63;
    if (lane == 0) { s_loc[wave] = locv; s_pc[wave] = pcv; s_np[wave] = npv; }
    __syncthreads();
    if (tid == 0) {
        float L = 0.0f, P = 0.0f; int N = 0;
        for (int w = 0; w < 4; ++w) { L += s_loc[w]; P += s_pc[w]; N += s_np[w]; }
        if (N) atomicAdd(&num_pos[b], N);
        atomicAdd(&loc_sum[b], L);
        atomicAdd(&posconf[b], P);
    }
}

// Kernel 3: per-image hard-negative mining: sum of top-k of neg_loss.
// Exact radix-select (4 x 8-bit rounds) on float bit patterns (all values >= +0).
// grid = BN, block = 1024. 128KB LDS for the per-image value array.
__global__ __launch_bounds__(1024) void k_topk(const float* __restrict__ conf,
                                               const unsigned char* __restrict__ posflag,
                                               const int* __restrict__ num_pos,
                                               float* __restrict__ negconf) {
    __shared__ float vals[AN];            // 128 KiB
    __shared__ unsigned int hist[256];
    __shared__ float red[16];
    __shared__ unsigned int s_sel, s_krem;

    int b = blockIdx.x;
    int tid = threadIdx.x;

    for (int i = tid; i < AN; i += 1024) {
        size_t idx = (size_t)b * AN + i;
        float p = conf[idx];
        float l = fmaxf(log1pf(-p), -100.0f);   // log(1-p), clamped like torch BCELoss
        float v = posflag[idx] ? 0.0f : -l;     // neg_loss (>= 0; exactly +0 for positives)
        vals[i] = v;
    }
    __syncthreads();

    int np = num_pos[b];
    int k = min(3 * np, AN - np);

    if (k > 0) {
        unsigned int prefix = 0;
        unsigned int krem = (unsigned int)k;
        for (int shift = 24; shift >= 0; shift -= 8) {
            if (tid < 256) hist[tid] = 0;
            __syncthreads();
            unsigned int hm = (shift == 24) ? 0u : (0xFFFFFFFFu << (shift + 8));
            for (int i = tid; i < AN; i += 1024) {
                unsigned int key = __float_as_uint(vals[i]);
                if ((key & hm) == prefix) atomicAdd(&hist[(key >> shift) & 0xFFu], 1u);
            }
            __syncthreads();
            if (tid == 0) {
                unsigned int cum = 0; int sel = 0; unsigned int nk = 1;
                for (int bb = 255; bb >= 0; --bb) {
                    unsigned int c = hist[bb];
                    if (cum + c >= krem) { sel = bb; nk = krem - cum; break; }
                    cum += c;
                }
                s_sel = (unsigned int)sel;
                s_krem = nk;
            }
            __syncthreads();
            prefix |= (s_sel << shift);
            krem = s_krem;
            __syncthreads();
        }
        float T = __uint_as_float(prefix);   // exact value of the k-th largest element
        float part = 0.0f;
        for (int i = tid; i < AN; i += 1024) {
            float v = vals[i];
            if (v > T) part += v;
        }
        for (int off = 32; off; off >>= 1) part += __shfl_xor(part, off);
        int wave = tid >> 6, lane = tid & 63;
        if (lane == 0) red[wave] = part;
        __syncthreads();
        if (tid == 0) {
            float t = 0.0f;
            for (int w = 0; w < 16; ++w) t += red[w];
            negconf[b] = t + (float)krem * T;    // krem copies of the boundary value
        }
    } else {
        if (tid == 0) negconf[b] = 0.0f;
    }
}

// Kernel 4: final reduction over images. 1 block, 64 threads.
__global__ void k_final(const int* __restrict__ num_pos,
                        const float* __restrict__ loc_sum,
                        const float* __restrict__ posconf,
                        const float* __restrict__ negconf,
                        float* __restrict__ out) {
    int tid = threadIdx.x;
    int np = 0; float lc = 0.0f, pc = 0.0f, nc = 0.0f;
    if (tid < BN) {
        np = num_pos[tid];
        lc = loc_sum[tid];
        pc = posconf[tid];
        nc = negconf[tid];
    }
    for (int off = 32; off; off >>= 1) {
        np += __shfl_xor(np, off);
        lc += __shfl_xor(lc, off);
        pc += __shfl_xor(pc, off);
        nc += __shfl_xor(nc, off);
    }
    if (tid == 0) {
        float tp = (float)max(1, np);
        float loc_loss = lc / tp;
        float conf_loss = (pc + nc) / tp;
        out[0] = loc_loss + conf_loss;
        out[1] = conf_loss;
        out[2] = loc_loss;
    }
}

extern "C" void kernel_launch(void* const* d_in, const int* in_sizes, int n_in,
                              void* d_out, int out_size, void* d_ws, size_t ws_size,
                              hipStream_t stream) {
    const float* bbox    = (const float*)d_in[0];   // [B,A,4]
    const float* conf    = (const float*)d_in[1];   // [B,A]
    const float* anchors = (const float*)d_in[2];   // [A,4]
    const float* gt      = (const float*)d_in[3];   // [B,G,4]
    float* out = (float*)d_out;

    // Zero flags + accumulators (deterministic per launch; graph-capture safe).
    hipMemsetAsync(d_ws, 0, 512 + (size_t)BN * AN, stream);

    dim3 g1(GN, BN);
    k_best_anchor<<<g1, 512, 0, stream>>>(anchors, gt, WS_POS(d_ws));

    dim3 g2(AN / 256, BN);
    k_anchor_pass<<<g2, 256, 0, stream>>>(bbox, conf, anchors, gt, WS_POS(d_ws),
                                          WS_NUMPOS(d_ws), WS_LOC(d_ws), WS_PCONF(d_ws));

    k_topk<<<BN, 1024, 0, stream>>>(conf, WS_POS(d_ws), WS_NUMPOS(d_ws), WS_NCONF(d_ws));

    k_final<<<1, 64, 0, stream>>>(WS_NUMPOS(d_ws), WS_LOC(d_ws), WS_PCONF(d_ws),
                                  WS_NCONF(d_ws), out);
}

// Round 3
// 176.745 us; speedup vs baseline: 1.5155x; 1.2175x over previous
//
#include <hip/hip_runtime.h>
#include <cmath>

#define BN 32
#define AN 32768
#define GN 64

// Workspace layout (bytes):
// [0,128):    int   num_pos[32]
// [128,256):  float loc_sum[32]
// [256,384):  float posconf[32]
// [384,512):  float negconf[32]
// [512, 512+BN*AN): u8 posflag[B*A]
#define WS_NUMPOS(ws)  ((int*)(ws))
#define WS_LOC(ws)     ((float*)((char*)(ws) + 128))
#define WS_PCONF(ws)   ((float*)((char*)(ws) + 256))
#define WS_NCONF(ws)   ((float*)((char*)(ws) + 384))
#define WS_POS(ws)     ((unsigned char*)((char*)(ws) + 512))

__device__ __forceinline__ float iou_val(float ax0, float ay0, float ax1, float ay1, float aarea,
                                         float gx0, float gy0, float gx1, float gy1, float garea) {
    float ix0 = fmaxf(ax0, gx0), iy0 = fmaxf(ay0, gy0);
    float ix1 = fminf(ax1, gx1), iy1 = fminf(ay1, gy1);
    float iw = fmaxf(ix1 - ix0, 0.0f), ih = fmaxf(iy1 - iy0, 0.0f);
    float inter = iw * ih;
    return inter / (aarea + garea - inter + 1e-6f);
}

// Kernel 1: per (image, gt) argmax over anchors of IoU -> force that anchor positive.
// One 512-thread block per (g, b). Packed u64 key = (iou_bits << 32) | ~anchor_idx
// (max key == max iou, ties -> min idx, matching jnp.argmax first-occurrence).
__global__ __launch_bounds__(512) void k_best_anchor(const float* __restrict__ anchors,
                                                     const float* __restrict__ gt,
                                                     unsigned char* __restrict__ posflag) {
    __shared__ unsigned long long sred[8];
    int g = blockIdx.x;
    int b = blockIdx.y;
    int tid = threadIdx.x;

    float4 gb = ((const float4*)gt)[b * GN + g];
    float garea = (gb.z - gb.x) * (gb.w - gb.y);

    float best = -1.0f;
    int bidx = 0;
    for (int a = tid; a < AN; a += 512) {
        float4 ab = ((const float4*)anchors)[a];
        float aarea = (ab.z - ab.x) * (ab.w - ab.y);
        float iou = iou_val(ab.x, ab.y, ab.z, ab.w, aarea, gb.x, gb.y, gb.z, gb.w, garea);
        if (iou > best) { best = iou; bidx = a; }  // strict > keeps smallest index in stride class
    }
    unsigned long long key = ((unsigned long long)__float_as_uint(best) << 32)
                           | (unsigned int)(~bidx);
    for (int off = 32; off; off >>= 1) {
        unsigned long long ok = __shfl_xor(key, off);
        key = (ok > key) ? ok : key;
    }
    int wave = tid >> 6, lane = tid & 63;
    if (lane == 0) sred[wave] = key;
    __syncthreads();
    if (tid == 0) {
        unsigned long long k = sred[0];
        for (int w = 1; w < 8; ++w) if (sred[w] > k) k = sred[w];
        int a = (int)(unsigned int)(~(unsigned int)k);
        posflag[(size_t)b * AN + a] = 1;
    }
}

// Kernel 2: per-anchor pass. best gt (max/argmax over G), pos mask, smooth-L1 loc, pos-BCE.
__global__ void k_anchor_pass(const float* __restrict__ bbox,
                              const float* __restrict__ conf,
                              const float* __restrict__ anchors,
                              const float* __restrict__ gt,
                              unsigned char* __restrict__ posflag,
                              int* __restrict__ num_pos,
                              float* __restrict__ loc_sum,
                              float* __restrict__ posconf) {
    __shared__ float4 sg[GN];     // gt corners
    __shared__ float  sga[GN];    // gt area
    __shared__ float4 sgcs[GN];   // gt center-size
    __shared__ float  s_loc[4], s_pc[4];
    __shared__ int    s_np[4];

    int b = blockIdx.y;
    int tid = threadIdx.x;
    if (tid < GN) {
        float4 g = ((const float4*)gt)[b * GN + tid];
        sg[tid] = g;
        sga[tid] = (g.z - g.x) * (g.w - g.y);
        sgcs[tid] = make_float4((g.x + g.z) * 0.5f, (g.y + g.w) * 0.5f, g.z - g.x, g.w - g.y);
    }
    __syncthreads();

    int a = blockIdx.x * 256 + tid;
    size_t ia = (size_t)b * AN + a;

    float4 ab = ((const float4*)anchors)[a];
    float aarea = (ab.z - ab.x) * (ab.w - ab.y);

    float best = -1.0f;
    int bidx = 0;
#pragma unroll 8
    for (int g = 0; g < GN; ++g) {
        float4 gb = sg[g];
        float iou = iou_val(ab.x, ab.y, ab.z, ab.w, aarea, gb.x, gb.y, gb.z, gb.w, sga[g]);
        if (iou > best) { best = iou; bidx = g; }  // first occurrence
    }

    bool p = (best > 0.5f) || (posflag[ia] != 0);
    posflag[ia] = p ? (unsigned char)1 : (unsigned char)0;

    float locv = 0.0f, pcv = 0.0f;
    if (p) {
        float4 bb = ((const float4*)bbox)[ia];
        float4 m = sgcs[bidx];
        float d0 = (bb.x + bb.z) * 0.5f - m.x;
        float d1 = (bb.y + bb.w) * 0.5f - m.y;
        float d2 = (bb.z - bb.x) - m.z;
        float d3 = (bb.w - bb.y) - m.w;
        float s = 0.0f;
        {
            float ad = fabsf(d0); s += (ad < 1.0f) ? 0.5f * d0 * d0 : ad - 0.5f;
            ad = fabsf(d1); s += (ad < 1.0f) ? 0.5f * d1 * d1 : ad - 0.5f;
            ad = fabsf(d2); s += (ad < 1.0f) ? 0.5f * d2 * d2 : ad - 0.5f;
            ad = fabsf(d3); s += (ad < 1.0f) ? 0.5f * d3 * d3 : ad - 0.5f;
        }
        locv = s;
        float pc = conf[ia];
        float lp = fmaxf(logf(pc), -100.0f);
        pcv = -lp;
    }
    int npv = p ? 1 : 0;

    for (int off = 32; off; off >>= 1) {
        locv += __shfl_xor(locv, off);
        pcv  += __shfl_xor(pcv, off);
        npv  += __shfl_xor(npv, off);
    }
    int wave = tid >> 6, lane = tid & 63;
    if (lane == 0) { s_loc[wave] = locv; s_pc[wave] = pcv; s_np[wave] = npv; }
    __syncthreads();
    if (tid == 0) {
        float L = 0.0f, P = 0.0f; int N = 0;
        for (int w = 0; w < 4; ++w) { L += s_loc[w]; P += s_pc[w]; N += s_np[w]; }
        if (N) atomicAdd(&num_pos[b], N);
        atomicAdd(&loc_sum[b], L);
        atomicAdd(&posconf[b], P);
    }
}

// Kernel 3: per-image hard-negative mining: sum of top-k of neg_loss.
// Exact radix-select, 3 rounds (12+12+8 bits) with a 4096-bin LDS histogram
// (spreads the hot exponent over 16 mantissa sub-bins -> low atomic contention)
// and a wave-parallel suffix-scan bin selection (no serial 256-bin walk).
// grid = BN, block = 1024. LDS: 128K vals + 16K hist.
__global__ __launch_bounds__(1024) void k_topk(const float* __restrict__ conf,
                                               const unsigned char* __restrict__ posflag,
                                               const int* __restrict__ num_pos,
                                               float* __restrict__ negconf) {
    __shared__ float vals[AN];               // 128 KiB
    __shared__ unsigned int hist[4096];      // 16 KiB
    __shared__ float red[16];
    __shared__ unsigned int s_sel, s_krem;

    int b = blockIdx.x;
    int tid = threadIdx.x;

    for (int i = tid; i < AN; i += 1024) {
        size_t idx = (size_t)b * AN + i;
        float p = conf[idx];
        float l = fmaxf(log1pf(-p), -100.0f);   // log(1-p), clamped like torch BCELoss
        vals[i] = posflag[idx] ? 0.0f : -l;     // neg_loss (>= 0; exactly +0 for positives)
    }
    __syncthreads();

    int np = num_pos[b];
    unsigned int k = (unsigned int)min(3 * np, AN - np);

    if (k > 0) {
        unsigned int prefix = 0;
        unsigned int krem = k;
        // rounds: (shift,width) = (20,12), (8,12), (0,8)
#pragma unroll
        for (int r = 0; r < 3; ++r) {
            const int shift = (r == 0) ? 20 : (r == 1) ? 8 : 0;
            const int width = (r == 2) ? 8 : 12;
            const unsigned int bmask = (1u << width) - 1u;
            const int hsh = shift + width;   // bits above must match prefix

            for (int i = tid; i < 4096; i += 1024) hist[i] = 0;
            __syncthreads();

            for (int i = tid; i < AN; i += 1024) {
                unsigned int key = __float_as_uint(vals[i]);
                bool m = (hsh >= 32) || ((key >> hsh) == (prefix >> hsh));
                if (m) atomicAdd(&hist[(key >> shift) & bmask], 1u);
            }
            __syncthreads();

            if (tid < 64) {
                // lane owns 64 consecutive bins; higher lane = higher bins
                int base = tid * 64;
                unsigned int c = 0;
#pragma unroll
                for (int i = 0; i < 64; ++i) c += hist[base + i];
                // inclusive suffix scan: S_l = sum_{m>=l} c_m
                unsigned int S = c;
#pragma unroll
                for (int d = 1; d < 64; d <<= 1) {
                    unsigned int t = __shfl_down(S, d);
                    if (tid + d < 64) S += t;
                }
                unsigned int E = S - c;          // sum over lanes > l
                if (E < krem && krem <= S) {     // unique boundary lane
                    unsigned int cum = E;
                    for (int bin = base + 63; bin >= base; --bin) {
                        unsigned int h = hist[bin];
                        cum += h;
                        if (cum >= krem) {
                            s_sel = (unsigned int)bin;
                            s_krem = krem - (cum - h);
                            break;
                        }
                    }
                }
            }
            __syncthreads();
            prefix |= (s_sel << shift);
            krem = s_krem;
            __syncthreads();   // protect s_sel/s_krem + hist before next round's zeroing
        }

        float T = __uint_as_float(prefix);   // exact value of the k-th largest element
        float part = 0.0f;
        for (int i = tid; i < AN; i += 1024) {
            float v = vals[i];
            if (v > T) part += v;
        }
        for (int off = 32; off; off >>= 1) part += __shfl_xor(part, off);
        int wave = tid >> 6, lane = tid & 63;
        if (lane == 0) red[wave] = part;
        __syncthreads();
        if (tid == 0) {
            float t = 0.0f;
            for (int w = 0; w < 16; ++w) t += red[w];
            negconf[b] = t + (float)krem * T;    // krem copies of the boundary value
        }
    } else {
        if (tid == 0) negconf[b] = 0.0f;
    }
}

// Kernel 4: final reduction over images. 1 block, 64 threads.
__global__ void k_final(const int* __restrict__ num_pos,
                        const float* __restrict__ loc_sum,
                        const float* __restrict__ posconf,
                        const float* __restrict__ negconf,
                        float* __restrict__ out) {
    int tid = threadIdx.x;
    int np = 0; float lc = 0.0f, pc = 0.0f, nc = 0.0f;
    if (tid < BN) {
        np = num_pos[tid];
        lc = loc_sum[tid];
        pc = posconf[tid];
        nc = negconf[tid];
    }
    for (int off = 32; off; off >>= 1) {
        np += __shfl_xor(np, off);
        lc += __shfl_xor(lc, off);
        pc += __shfl_xor(pc, off);
        nc += __shfl_xor(nc, off);
    }
    if (tid == 0) {
        float tp = (float)max(1, np);
        float loc_loss = lc / tp;
        float conf_loss = (pc + nc) / tp;
        out[0] = loc_loss + conf_loss;
        out[1] = conf_loss;
        out[2] = loc_loss;
    }
}

extern "C" void kernel_launch(void* const* d_in, const int* in_sizes, int n_in,
                              void* d_out, int out_size, void* d_ws, size_t ws_size,
                              hipStream_t stream) {
    const float* bbox    = (const float*)d_in[0];   // [B,A,4]
    const float* conf    = (const float*)d_in[1];   // [B,A]
    const float* anchors = (const float*)d_in[2];   // [A,4]
    const float* gt      = (const float*)d_in[3];   // [B,G,4]
    float* out = (float*)d_out;

    // Zero flags + accumulators (deterministic per launch; graph-capture safe).
    hipMemsetAsync(d_ws, 0, 512 + (size_t)BN * AN, stream);

    dim3 g1(GN, BN);
    k_best_anchor<<<g1, 512, 0, stream>>>(anchors, gt, WS_POS(d_ws));

    dim3 g2(AN / 256, BN);
    k_anchor_pass<<<g2, 256, 0, stream>>>(bbox, conf, anchors, gt, WS_POS(d_ws),
                                          WS_NUMPOS(d_ws), WS_LOC(d_ws), WS_PCONF(d_ws));

    k_topk<<<BN, 1024, 0, stream>>>(conf, WS_POS(d_ws), WS_NUMPOS(d_ws), WS_NCONF(d_ws));

    k_final<<<1, 64, 0, stream>>>(WS_NUMPOS(d_ws), WS_LOC(d_ws), WS_PCONF(d_ws),
                                  WS_NCONF(d_ws), out);
}

// Round 4
// 116.430 us; speedup vs baseline: 2.3006x; 1.5180x over previous
//
#include <hip/hip_runtime.h>
#include <cmath>

#define BN 32
#define AN 32768
#define GN 64
#define APT 4                      // anchors per thread in k_fused
#define TPB 256                    // threads per block in k_fused
#define ANCH_PER_BLK (APT * TPB)   // 1024

// ---------------- fast-path workspace layout (bytes) ----------------
// [0,128):    int   num_pos[32]
// [128,256):  float loc_sum[32]
// [256,384):  float posconf[32]
// [384,512):  float negconf[32]
// [512, 512+2048*8):   u64 gkey[B*G]   (per-(b,g) best-anchor key, atomicMax)
// [16896, 16896+B*A):  u8  abyte[B*A]  (bit7 = iou>0.5, bits5:0 = matched g)
#define WS_NUMPOS(ws)  ((int*)(ws))
#define WS_LOC(ws)     ((float*)((char*)(ws) + 128))
#define WS_PCONF(ws)   ((float*)((char*)(ws) + 256))
#define WS_NCONF(ws)   ((float*)((char*)(ws) + 384))
#define WS_GKEY(ws)    ((unsigned long long*)((char*)(ws) + 512))
#define WS_ABYTE(ws)   ((unsigned char*)((char*)(ws) + 16896))
#define WS_FAST_NEED   (16896 + (size_t)BN * AN)

// fallback layout: posflag u8[B*A] at +512 (round-3 proven path)
#define WS_POS(ws)     ((unsigned char*)((char*)(ws) + 512))
#define WS_FB_NEED     (512 + (size_t)BN * AN)

__device__ __forceinline__ float iou_exact(float4 a, float aarea,
                                           float4 g, float garea) {
    float ix0 = fmaxf(a.x, g.x), iy0 = fmaxf(a.y, g.y);
    float ix1 = fminf(a.z, g.z), iy1 = fminf(a.w, g.w);
    float iw = fmaxf(ix1 - ix0, 0.0f), ih = fmaxf(iy1 - iy0, 0.0f);
    float inter = iw * ih;
    return inter / (aarea + garea - inter + 1e-6f);
}

// ===================== FAST PATH =====================

// Fused IoU pass: computes every (anchor, gt) IoU exactly once.
// - per-anchor best over g (thread-local, tie -> min g) -> compressed byte
// - per-gt best over anchors via rotation + shfl-pull into packed u64 keys
//   key = (iou_bits<<32) | ~anchor_idx  (max key == max iou, tie -> min idx)
// grid = (AN/1024, BN), block = 256, 4 anchors/thread.
__global__ __launch_bounds__(TPB) void k_fused(const float* __restrict__ anchors,
                                               const float* __restrict__ gt,
                                               unsigned long long* __restrict__ gkey,
                                               unsigned char* __restrict__ abyte) {
    __shared__ float4 sg[GN];
    __shared__ float  sga[GN];
    __shared__ unsigned long long skey[4][GN];

    int b = blockIdx.y;
    int tid = threadIdx.x;
    int lane = tid & 63, wave = tid >> 6;
    int blockbase = blockIdx.x * ANCH_PER_BLK;

    if (tid < GN) {
        float4 g = ((const float4*)gt)[b * GN + tid];
        sg[tid] = g;
        sga[tid] = (g.z - g.x) * (g.w - g.y);
    }
    __syncthreads();

    float4 ab[APT];
    float  sa[APT];                 // anchor area + 1e-6 folded in
    unsigned long long abest[APT];  // hi = iou bits, lo = (63 - g)
    unsigned long long gacc[APT];   // per-gt accumulator for gt == lane
#pragma unroll
    for (int k = 0; k < APT; ++k) {
        int a = blockbase + k * TPB + tid;
        ab[k] = ((const float4*)anchors)[a];
        sa[k] = (ab[k].z - ab[k].x) * (ab[k].w - ab[k].y) + 1e-6f;
        abest[k] = 0ull;
        gacc[k] = 0ull;
    }

    for (int j = 0; j < GN; ++j) {
        int g = (lane + j) & 63;
        float4 gb = sg[g];
        float sgA = sga[g];
        int src = (lane - j) & 63;
        unsigned long long glo = (unsigned long long)(unsigned)(63 - g);

        float iou[APT];
#pragma unroll
        for (int k = 0; k < APT; ++k) {
            float ix0 = fmaxf(ab[k].x, gb.x), iy0 = fmaxf(ab[k].y, gb.y);
            float ix1 = fminf(ab[k].z, gb.z), iy1 = fminf(ab[k].w, gb.w);
            float iw = fmaxf(ix1 - ix0, 0.0f), ih = fmaxf(iy1 - iy0, 0.0f);
            float inter = iw * ih;
            float denom = (sa[k] + sgA) - inter;
            float v = inter * __builtin_amdgcn_rcpf(denom);
            iou[k] = v;
            unsigned long long key = ((unsigned long long)__float_as_uint(v) << 32) | glo;
            if (key > abest[k]) abest[k] = key;
        }
#pragma unroll
        for (int k = 0; k < APT; ++k) {
            float piou = __shfl(iou[k], src, 64);
            unsigned idx = (unsigned)(blockbase + k * TPB + wave * 64 + src);
            unsigned long long pkey =
                ((unsigned long long)__float_as_uint(piou) << 32) | (unsigned long long)(~idx);
            if (pkey > gacc[k]) gacc[k] = pkey;
        }
    }

    // per-anchor results -> compressed byte (bit7 = best_iou>0.5, bits5:0 = g)
#pragma unroll
    for (int k = 0; k < APT; ++k) {
        float biou = __uint_as_float((unsigned)(abest[k] >> 32));
        unsigned gsel = 63u - (unsigned)(abest[k] & 63ull);
        unsigned char byte = (unsigned char)(((biou > 0.5f) ? 0x80u : 0u) | gsel);
        abyte[(size_t)b * AN + blockbase + k * TPB + tid] = byte;
    }

    // per-gt: combine the APT slots, then waves, then global atomicMax
    unsigned long long gk = gacc[0];
#pragma unroll
    for (int k = 1; k < APT; ++k) if (gacc[k] > gk) gk = gacc[k];
    skey[wave][lane] = gk;
    __syncthreads();
    if (tid < GN) {
        unsigned long long kk = skey[0][tid];
#pragma unroll
        for (int w = 1; w < 4; ++w) if (skey[w][tid] > kk) kk = skey[w][tid];
        atomicMax(&gkey[b * GN + tid], kk);
    }
}

// Per-image tail: pos mask (byte | forced bitmap), num_pos, smooth-L1 loc,
// pos-BCE, then exact radix top-k sum of neg_loss (3 rounds, 4096-bin hist).
// grid = BN, block = 1024.
__global__ __launch_bounds__(1024) void k_tail(const float* __restrict__ bbox,
                                               const float* __restrict__ conf,
                                               const float* __restrict__ gt,
                                               const unsigned long long* __restrict__ gkey,
                                               const unsigned char* __restrict__ abyte,
                                               int* __restrict__ num_pos,
                                               float* __restrict__ loc_sum,
                                               float* __restrict__ posconf,
                                               float* __restrict__ negconf) {
    __shared__ float vals[AN];               // 128 KiB
    __shared__ unsigned int hist[4096];      // 16 KiB
    __shared__ unsigned int bitmap[AN / 32]; // 4 KiB
    __shared__ float4 sgcs[GN];              // 1 KiB (gt center-size)
    __shared__ float redL[16], redP[16];
    __shared__ int   redN[16];
    __shared__ int   s_np;
    __shared__ unsigned int s_sel, s_krem;

    int b = blockIdx.x;
    int tid = threadIdx.x;

    for (int i = tid; i < AN / 32; i += 1024) bitmap[i] = 0;
    if (tid < GN) {
        float4 g = ((const float4*)gt)[b * GN + tid];
        sgcs[tid] = make_float4((g.x + g.z) * 0.5f, (g.y + g.w) * 0.5f,
                                g.z - g.x, g.w - g.y);
    }
    __syncthreads();
    if (tid < GN) {
        unsigned long long kk = gkey[b * GN + tid];
        unsigned idx = ~(unsigned)(kk & 0xFFFFFFFFull);
        atomicOr(&bitmap[idx >> 5], 1u << (idx & 31));
    }
    __syncthreads();

    float locv = 0.0f, pcv = 0.0f;
    int npv = 0;
    for (int i = tid; i < AN; i += 1024) {
        size_t ia = (size_t)b * AN + i;
        unsigned byte = abyte[ia];
        float p = conf[ia];
        bool forced = (bitmap[i >> 5] >> (i & 31)) & 1u;
        bool pos = (byte & 0x80u) || forced;
        float v;
        if (pos) {
            float4 bb = ((const float4*)bbox)[ia];
            float4 m = sgcs[byte & 63u];
            float d0 = (bb.x + bb.z) * 0.5f - m.x;
            float d1 = (bb.y + bb.w) * 0.5f - m.y;
            float d2 = (bb.z - bb.x) - m.z;
            float d3 = (bb.w - bb.y) - m.w;
            float ad = fabsf(d0); float s = (ad < 1.0f) ? 0.5f * d0 * d0 : ad - 0.5f;
            ad = fabsf(d1); s += (ad < 1.0f) ? 0.5f * d1 * d1 : ad - 0.5f;
            ad = fabsf(d2); s += (ad < 1.0f) ? 0.5f * d2 * d2 : ad - 0.5f;
            ad = fabsf(d3); s += (ad < 1.0f) ? 0.5f * d3 * d3 : ad - 0.5f;
            locv += s;
            pcv += -fmaxf(logf(p), -100.0f);
            v = 0.0f;
            npv += 1;
        } else {
            v = -fmaxf(log1pf(-p), -100.0f);   // neg_loss > 0
        }
        vals[i] = v;
    }
    // block reduce np/loc/pbce
    for (int off = 32; off; off >>= 1) {
        locv += __shfl_xor(locv, off);
        pcv  += __shfl_xor(pcv, off);
        npv  += __shfl_xor(npv, off);
    }
    int wave = tid >> 6, lane = tid & 63;
    if (lane == 0) { redL[wave] = locv; redP[wave] = pcv; redN[wave] = npv; }
    __syncthreads();
    if (tid == 0) {
        float L = 0.0f, P = 0.0f; int N = 0;
        for (int w = 0; w < 16; ++w) { L += redL[w]; P += redP[w]; N += redN[w]; }
        num_pos[b] = N; loc_sum[b] = L; posconf[b] = P; s_np = N;
    }
    __syncthreads();

    int np = s_np;
    unsigned int k = (unsigned int)min(3 * np, AN - np);
    if (k > 0) {
        unsigned int prefix = 0;
        unsigned int krem = k;
#pragma unroll
        for (int r = 0; r < 3; ++r) {
            const int shift = (r == 0) ? 20 : (r == 1) ? 8 : 0;
            const int width = (r == 2) ? 8 : 12;
            const unsigned int bmask = (1u << width) - 1u;
            const int hsh = shift + width;

            for (int i = tid; i < 4096; i += 1024) hist[i] = 0;
            __syncthreads();
            for (int i = tid; i < AN; i += 1024) {
                unsigned int key = __float_as_uint(vals[i]);
                bool m = (hsh >= 32) || ((key >> hsh) == (prefix >> hsh));
                if (m) atomicAdd(&hist[(key >> shift) & bmask], 1u);
            }
            __syncthreads();
            if (tid < 64) {
                int base = tid * 64;
                unsigned int c = 0;
#pragma unroll
                for (int i = 0; i < 64; ++i) c += hist[base + i];
                unsigned int S = c;
#pragma unroll
                for (int d = 1; d < 64; d <<= 1) {
                    unsigned int t = __shfl_down(S, d);
                    if (tid + d < 64) S += t;
                }
                unsigned int E = S - c;
                if (E < krem && krem <= S) {
                    unsigned int cum = E;
                    for (int bin = base + 63; bin >= base; --bin) {
                        unsigned int h = hist[bin];
                        cum += h;
                        if (cum >= krem) {
                            s_sel = (unsigned int)bin;
                            s_krem = krem - (cum - h);
                            break;
                        }
                    }
                }
            }
            __syncthreads();
            prefix |= (s_sel << shift);
            krem = s_krem;
            __syncthreads();
        }
        float T = __uint_as_float(prefix);
        float part = 0.0f;
        for (int i = tid; i < AN; i += 1024) {
            float v = vals[i];
            if (v > T) part += v;
        }
        for (int off = 32; off; off >>= 1) part += __shfl_xor(part, off);
        if (lane == 0) redL[wave] = part;
        __syncthreads();
        if (tid == 0) {
            float t = 0.0f;
            for (int w = 0; w < 16; ++w) t += redL[w];
            negconf[b] = t + (float)krem * T;
        }
    } else {
        if (tid == 0) negconf[b] = 0.0f;
    }
}

// ===================== FALLBACK PATH (round-3, proven) =====================

__global__ __launch_bounds__(512) void fb_best_anchor(const float* __restrict__ anchors,
                                                      const float* __restrict__ gt,
                                                      unsigned char* __restrict__ posflag) {
    __shared__ unsigned long long sred[8];
    int g = blockIdx.x, b = blockIdx.y, tid = threadIdx.x;
    float4 gb = ((const float4*)gt)[b * GN + g];
    float garea = (gb.z - gb.x) * (gb.w - gb.y);
    float best = -1.0f; int bidx = 0;
    for (int a = tid; a < AN; a += 512) {
        float4 ab = ((const float4*)anchors)[a];
        float aarea = (ab.z - ab.x) * (ab.w - ab.y);
        float iou = iou_exact(ab, aarea, gb, garea);
        if (iou > best) { best = iou; bidx = a; }
    }
    unsigned long long key = ((unsigned long long)__float_as_uint(best) << 32)
                           | (unsigned int)(~bidx);
    for (int off = 32; off; off >>= 1) {
        unsigned long long ok = __shfl_xor(key, off);
        key = (ok > key) ? ok : key;
    }
    int wave = tid >> 6, lane = tid & 63;
    if (lane == 0) sred[wave] = key;
    __syncthreads();
    if (tid == 0) {
        unsigned long long k = sred[0];
        for (int w = 1; w < 8; ++w) if (sred[w] > k) k = sred[w];
        posflag[(size_t)b * AN + (unsigned)(~(unsigned int)k)] = 1;
    }
}

__global__ void fb_anchor_pass(const float* __restrict__ bbox,
                               const float* __restrict__ conf,
                               const float* __restrict__ anchors,
                               const float* __restrict__ gt,
                               unsigned char* __restrict__ posflag,
                               int* __restrict__ num_pos,
                               float* __restrict__ loc_sum,
                               float* __restrict__ posconf) {
    __shared__ float4 sg[GN]; __shared__ float sga[GN]; __shared__ float4 sgcs[GN];
    __shared__ float s_loc[4], s_pc[4]; __shared__ int s_np[4];
    int b = blockIdx.y, tid = threadIdx.x;
    if (tid < GN) {
        float4 g = ((const float4*)gt)[b * GN + tid];
        sg[tid] = g; sga[tid] = (g.z - g.x) * (g.w - g.y);
        sgcs[tid] = make_float4((g.x + g.z) * 0.5f, (g.y + g.w) * 0.5f, g.z - g.x, g.w - g.y);
    }
    __syncthreads();
    int a = blockIdx.x * 256 + tid;
    size_t ia = (size_t)b * AN + a;
    float4 ab = ((const float4*)anchors)[a];
    float aarea = (ab.z - ab.x) * (ab.w - ab.y);
    float best = -1.0f; int bidx = 0;
#pragma unroll 8
    for (int g = 0; g < GN; ++g) {
        float iou = iou_exact(ab, aarea, sg[g], sga[g]);
        if (iou > best) { best = iou; bidx = g; }
    }
    bool p = (best > 0.5f) || (posflag[ia] != 0);
    posflag[ia] = p ? 1 : 0;
    float locv = 0.0f, pcv = 0.0f;
    if (p) {
        float4 bb = ((const float4*)bbox)[ia];
        float4 m = sgcs[bidx];
        float d0 = (bb.x + bb.z) * 0.5f - m.x, d1 = (bb.y + bb.w) * 0.5f - m.y;
        float d2 = (bb.z - bb.x) - m.z, d3 = (bb.w - bb.y) - m.w;
        float ad = fabsf(d0); float s = (ad < 1.0f) ? 0.5f * d0 * d0 : ad - 0.5f;
        ad = fabsf(d1); s += (ad < 1.0f) ? 0.5f * d1 * d1 : ad - 0.5f;
        ad = fabsf(d2); s += (ad < 1.0f) ? 0.5f * d2 * d2 : ad - 0.5f;
        ad = fabsf(d3); s += (ad < 1.0f) ? 0.5f * d3 * d3 : ad - 0.5f;
        locv = s; pcv = -fmaxf(logf(conf[ia]), -100.0f);
    }
    int npv = p ? 1 : 0;
    for (int off = 32; off; off >>= 1) {
        locv += __shfl_xor(locv, off); pcv += __shfl_xor(pcv, off); npv += __shfl_xor(npv, off);
    }
    int wave = tid >> 6, lane = tid & 63;
    if (lane == 0) { s_loc[wave] = locv; s_pc[wave] = pcv; s_np[wave] = npv; }
    __syncthreads();
    if (tid == 0) {
        float L = 0, P = 0; int N = 0;
        for (int w = 0; w < 4; ++w) { L += s_loc[w]; P += s_pc[w]; N += s_np[w]; }
        if (N) atomicAdd(&num_pos[b], N);
        atomicAdd(&loc_sum[b], L); atomicAdd(&posconf[b], P);
    }
}

__global__ __launch_bounds__(1024) void fb_topk(const float* __restrict__ conf,
                                                const unsigned char* __restrict__ posflag,
                                                const int* __restrict__ num_pos,
                                                float* __restrict__ negconf) {
    __shared__ float vals[AN];
    __shared__ unsigned int hist[4096];
    __shared__ float red[16];
    __shared__ unsigned int s_sel, s_krem;
    int b = blockIdx.x, tid = threadIdx.x;
    for (int i = tid; i < AN; i += 1024) {
        size_t idx = (size_t)b * AN + i;
        float l = fmaxf(log1pf(-conf[idx]), -100.0f);
        vals[i] = posflag[idx] ? 0.0f : -l;
    }
    __syncthreads();
    int np = num_pos[b];
    unsigned int k = (unsigned int)min(3 * np, AN - np);
    if (k > 0) {
        unsigned int prefix = 0, krem = k;
#pragma unroll
        for (int r = 0; r < 3; ++r) {
            const int shift = (r == 0) ? 20 : (r == 1) ? 8 : 0;
            const int width = (r == 2) ? 8 : 12;
            const unsigned int bmask = (1u << width) - 1u;
            const int hsh = shift + width;
            for (int i = tid; i < 4096; i += 1024) hist[i] = 0;
            __syncthreads();
            for (int i = tid; i < AN; i += 1024) {
                unsigned int key = __float_as_uint(vals[i]);
                bool m = (hsh >= 32) || ((key >> hsh) == (prefix >> hsh));
                if (m) atomicAdd(&hist[(key >> shift) & bmask], 1u);
            }
            __syncthreads();
            if (tid < 64) {
                int base = tid * 64; unsigned int c = 0;
#pragma unroll
                for (int i = 0; i < 64; ++i) c += hist[base + i];
                unsigned int S = c;
#pragma unroll
                for (int d = 1; d < 64; d <<= 1) {
                    unsigned int t = __shfl_down(S, d);
                    if (tid + d < 64) S += t;
                }
                unsigned int E = S - c;
                if (E < krem && krem <= S) {
                    unsigned int cum = E;
                    for (int bin = base + 63; bin >= base; --bin) {
                        unsigned int h = hist[bin]; cum += h;
                        if (cum >= krem) { s_sel = bin; s_krem = krem - (cum - h); break; }
                    }
                }
            }
            __syncthreads();
            prefix |= (s_sel << shift); krem = s_krem;
            __syncthreads();
        }
        float T = __uint_as_float(prefix);
        float part = 0.0f;
        for (int i = tid; i < AN; i += 1024) { float v = vals[i]; if (v > T) part += v; }
        for (int off = 32; off; off >>= 1) part += __shfl_xor(part, off);
        int wave = tid >> 6, lane = tid & 63;
        if (lane == 0) red[wave] = part;
        __syncthreads();
        if (tid == 0) {
            float t = 0.0f;
            for (int w = 0; w < 16; ++w) t += red[w];
            negconf[b] = t + (float)krem * T;
        }
    } else if (tid == 0) negconf[b] = 0.0f;
}

// ===================== final reduction (shared) =====================
__global__ void k_final(const int* __restrict__ num_pos,
                        const float* __restrict__ loc_sum,
                        const float* __restrict__ posconf,
                        const float* __restrict__ negconf,
                        float* __restrict__ out) {
    int tid = threadIdx.x;
    int np = 0; float lc = 0.0f, pc = 0.0f, nc = 0.0f;
    if (tid < BN) { np = num_pos[tid]; lc = loc_sum[tid]; pc = posconf[tid]; nc = negconf[tid]; }
    for (int off = 32; off; off >>= 1) {
        np += __shfl_xor(np, off); lc += __shfl_xor(lc, off);
        pc += __shfl_xor(pc, off); nc += __shfl_xor(nc, off);
    }
    if (tid == 0) {
        float tp = (float)max(1, np);
        float loc_loss = lc / tp;
        float conf_loss = (pc + nc) / tp;
        out[0] = loc_loss + conf_loss;
        out[1] = conf_loss;
        out[2] = loc_loss;
    }
}

extern "C" void kernel_launch(void* const* d_in, const int* in_sizes, int n_in,
                              void* d_out, int out_size, void* d_ws, size_t ws_size,
                              hipStream_t stream) {
    const float* bbox    = (const float*)d_in[0];   // [B,A,4]
    const float* conf    = (const float*)d_in[1];   // [B,A]
    const float* anchors = (const float*)d_in[2];   // [A,4]
    const float* gt      = (const float*)d_in[3];   // [B,G,4]
    float* out = (float*)d_out;

    if (ws_size >= WS_FAST_NEED) {
        // zero only gkey (scalars are written directly by k_tail)
        hipMemsetAsync((char*)d_ws + 512, 0, 16384, stream);

        dim3 g1(AN / ANCH_PER_BLK, BN);   // (32, 32)
        k_fused<<<g1, TPB, 0, stream>>>(anchors, gt, WS_GKEY(d_ws), WS_ABYTE(d_ws));

        k_tail<<<BN, 1024, 0, stream>>>(bbox, conf, gt, WS_GKEY(d_ws), WS_ABYTE(d_ws),
                                        WS_NUMPOS(d_ws), WS_LOC(d_ws), WS_PCONF(d_ws),
                                        WS_NCONF(d_ws));

        k_final<<<1, 64, 0, stream>>>(WS_NUMPOS(d_ws), WS_LOC(d_ws), WS_PCONF(d_ws),
                                      WS_NCONF(d_ws), out);
    } else {
        // proven round-3 path
        hipMemsetAsync(d_ws, 0, WS_FB_NEED, stream);
        dim3 g1(GN, BN);
        fb_best_anchor<<<g1, 512, 0, stream>>>(anchors, gt, WS_POS(d_ws));
        dim3 g2(AN / 256, BN);
        fb_anchor_pass<<<g2, 256, 0, stream>>>(bbox, conf, anchors, gt, WS_POS(d_ws),
                                               WS_NUMPOS(d_ws), WS_LOC(d_ws), WS_PCONF(d_ws));
        fb_topk<<<BN, 1024, 0, stream>>>(conf, WS_POS(d_ws), WS_NUMPOS(d_ws), WS_NCONF(d_ws));
        k_final<<<1, 64, 0, stream>>>(WS_NUMPOS(d_ws), WS_LOC(d_ws), WS_PCONF(d_ws),
                                      WS_NCONF(d_ws), out);
    }
}